// Round 1
// baseline (2849.293 us; speedup 1.0000x reference)
//
#include <hip/hip_runtime.h>
#include <hip/hip_bf16.h>
#include <stdint.h>

typedef unsigned short ushort_t;
typedef unsigned int uint_t;

#define B_ 512
#define S_ 256
#define T_ 10
#define V_ 28
#define E_ 32
#define H_ 128
#define G4_ 512  // 4H

// ---- workspace layout (float element offsets) ----
// xt_f[28*512] xt_b xt_d | WhhT_f[128*512] WhhT_b WhhT_d | attn_WT[256*128] | out_WT[128*28]
// hfin[2*512*128] cfin[2*512*128] | then bf16 hs[512*256*256]
#define XT_F   0
#define XT_B   14336
#define XT_D   28672
#define WT_F   43008
#define WT_B   108544
#define WT_D   174080
#define AWT    239616
#define OWT    272384
#define HFIN   275968
#define CFIN   407040
#define WS_FLOATS 538112
#define HS_BYTE_OFF (538112ull * 4ull)   // 2,152,448
#define PREP_N 275968

__device__ __forceinline__ float fast_exp2(float x) { return __builtin_amdgcn_exp2f(x); }
__device__ __forceinline__ float fast_rcp(float x)  { return __builtin_amdgcn_rcpf(x); }
__device__ __forceinline__ float sigm(float x) {
    return fast_rcp(1.f + fast_exp2(-1.4426950408889634f * x));
}
__device__ __forceinline__ float tanh_(float x) {
    // tanh(x) = 1 - 2/(1+e^{2x}); saturates correctly for |x| large
    return 1.f - 2.f * fast_rcp(1.f + fast_exp2(2.8853900817779268f * x));
}
__device__ __forceinline__ ushort_t f2bf(float x) {
    uint_t u = __float_as_uint(x);
    return (ushort_t)((u + 0x7FFFu + ((u >> 16) & 1u)) >> 16);  // RNE
}
__device__ __forceinline__ float bflo(uint_t u) { return __uint_as_float(u << 16); }
__device__ __forceinline__ float bfhi(uint_t u) { return __uint_as_float(u & 0xFFFF0000u); }

// ---------------- prep: xg tables (28 distinct tokens!) + weight transposes ----------------
__global__ __launch_bounds__(256) void prep_kernel(
    const float* __restrict__ embed,
    const float* __restrict__ Wih_f, const float* __restrict__ b_f,
    const float* __restrict__ Wih_b, const float* __restrict__ b_b,
    const float* __restrict__ Wih_d, const float* __restrict__ b_d,
    const float* __restrict__ Whh_f, const float* __restrict__ Whh_b,
    const float* __restrict__ Whh_d,
    const float* __restrict__ attn_W, const float* __restrict__ out_W,
    float* __restrict__ ws)
{
    int i = blockIdx.x * 256 + threadIdx.x;
    if (i < 43008) {                       // xg tables: table[v][j] = b[j] + sum_e embed[v,e]*Wih[j,e]
        int tbl = i / 14336, rem = i % 14336;
        int v = rem >> 9, jj = rem & 511;
        const float* Wih = (tbl == 0) ? Wih_f : (tbl == 1) ? Wih_b : Wih_d;
        const float* bb  = (tbl == 0) ? b_f   : (tbl == 1) ? b_b   : b_d;
        float acc = bb[jj];
        #pragma unroll
        for (int e = 0; e < 32; ++e) acc = fmaf(embed[v * 32 + e], Wih[jj * 32 + e], acc);
        ws[tbl * 14336 + rem] = acc;
    } else if (i < 43008 + 196608) {       // WhhT[k][j] = Whh[j][k]
        int r = i - 43008; int tbl = r / 65536; int rem = r % 65536;
        int k = rem >> 9, jj = rem & 511;
        const float* Whh = (tbl == 0) ? Whh_f : (tbl == 1) ? Whh_b : Whh_d;
        ws[WT_F + tbl * 65536 + k * 512 + jj] = Whh[jj * 128 + k];
    } else if (i < AWT + 32768) {          // attn_WT[k][u] = attn_W[u][k]
        int r = i - AWT; int k = r >> 7, uu = r & 127;
        ws[AWT + k * 128 + uu] = attn_W[uu * 256 + k];
    } else if (i < OWT + 3584) {           // out_WT[k][v] = out_W[v][k]
        int r = i - OWT; int k = r / 28, v = r % 28;
        ws[OWT + k * 28 + v] = out_W[v * 128 + k];
    }
}

// ---------------- encoder: one block = 4 batch rows x one direction, all 256 steps ----------------
// thread j owns gate-column j; Whh^T column in 128 VGPRs; h broadcast from LDS.
__global__ __launch_bounds__(512, 2) void enc_kernel(
    const int* __restrict__ src,
    const float* __restrict__ xt_base,   // ws+XT_F (dir offset in-kernel)
    const float* __restrict__ wt_base,   // ws+WT_F
    float* __restrict__ hfin_base,       // ws+HFIN
    float* __restrict__ cfin_base,       // ws+CFIN
    ushort_t* __restrict__ hs)           // bf16 [B][S][2H]
{
    const int dir = blockIdx.y;
    const int b0 = blockIdx.x * 4;
    const int tid = threadIdx.x;
    const int j = tid;

    const float* xt   = xt_base + dir * 14336;
    const float* WhhT = wt_base + dir * 65536;

    __shared__ __align__(16) float xt_lds[28 * 512];
    __shared__ __align__(16) float h_lds[4][128];
    __shared__ __align__(16) float g_lds[4][512];
    __shared__ int tok_lds[4 * 256];

    for (int i = tid; i < 28 * 512; i += 512) xt_lds[i] = xt[i];
    for (int i = tid; i < 4 * 256; i += 512) {
        int r = i >> 8, s = i & 255;
        tok_lds[i] = src[(b0 + r) * S_ + s];
    }
    h_lds[tid >> 7][tid & 127] = 0.f;

    float4 w4[32];
    #pragma unroll
    for (int kc = 0; kc < 32; ++kc) {
        w4[kc].x = WhhT[(kc * 4 + 0) * 512 + j];
        w4[kc].y = WhhT[(kc * 4 + 1) * 512 + j];
        w4[kc].z = WhhT[(kc * 4 + 2) * 512 + j];
        w4[kc].w = WhhT[(kc * 4 + 3) * 512 + j];
    }

    const int rr = tid >> 7, u = tid & 127;
    float c = 0.f, hlast = 0.f;
    __syncthreads();

    for (int t = 0; t < S_; ++t) {
        const int pos = dir ? (S_ - 1 - t) : t;
        float a0 = xt_lds[tok_lds[0 * 256 + pos] * 512 + j];
        float a1 = xt_lds[tok_lds[1 * 256 + pos] * 512 + j];
        float a2 = xt_lds[tok_lds[2 * 256 + pos] * 512 + j];
        float a3 = xt_lds[tok_lds[3 * 256 + pos] * 512 + j];
        #pragma unroll
        for (int kc = 0; kc < 32; ++kc) {
            const float4 w = w4[kc];
            const float4 h0 = *reinterpret_cast<const float4*>(&h_lds[0][kc * 4]);
            const float4 h1 = *reinterpret_cast<const float4*>(&h_lds[1][kc * 4]);
            const float4 h2 = *reinterpret_cast<const float4*>(&h_lds[2][kc * 4]);
            const float4 h3 = *reinterpret_cast<const float4*>(&h_lds[3][kc * 4]);
            a0 = fmaf(h0.x, w.x, a0); a0 = fmaf(h0.y, w.y, a0); a0 = fmaf(h0.z, w.z, a0); a0 = fmaf(h0.w, w.w, a0);
            a1 = fmaf(h1.x, w.x, a1); a1 = fmaf(h1.y, w.y, a1); a1 = fmaf(h1.z, w.z, a1); a1 = fmaf(h1.w, w.w, a1);
            a2 = fmaf(h2.x, w.x, a2); a2 = fmaf(h2.y, w.y, a2); a2 = fmaf(h2.z, w.z, a2); a2 = fmaf(h2.w, w.w, a2);
            a3 = fmaf(h3.x, w.x, a3); a3 = fmaf(h3.y, w.y, a3); a3 = fmaf(h3.z, w.z, a3); a3 = fmaf(h3.w, w.w, a3);
        }
        g_lds[0][j] = a0; g_lds[1][j] = a1; g_lds[2][j] = a2; g_lds[3][j] = a3;
        __syncthreads();
        {
            float gi = g_lds[rr][u], gf = g_lds[rr][u + 128];
            float gg = g_lds[rr][u + 256], go = g_lds[rr][u + 384];
            float ii = sigm(gi), ff = sigm(gf), g_ = tanh_(gg), oo = sigm(go);
            c = ff * c + ii * g_;
            float h = oo * tanh_(c);
            hlast = h;
            h_lds[rr][u] = h;
            hs[((size_t)(b0 + rr) * S_ + pos) * 256 + u + dir * 128] = f2bf(h);
        }
        __syncthreads();
    }
    hfin_base[dir * 65536 + (b0 + rr) * 128 + u] = hlast;
    cfin_base[dir * 65536 + (b0 + rr) * 128 + u] = c;
}

// ---------------- decoder: one block = 2 batch rows, all 10 steps ----------------
__global__ __launch_bounds__(512, 2) void dec_kernel(
    const int* __restrict__ target,
    const float* __restrict__ xt_d,      // ws+XT_D
    const float* __restrict__ WhhT_d,    // ws+WT_D
    const float* __restrict__ hfin, const float* __restrict__ cfin,
    const float* __restrict__ proj_W, const float* __restrict__ proj_b,
    const float* __restrict__ attn_WT, const float* __restrict__ attn_b,
    const float* __restrict__ out_WT, const float* __restrict__ out_b,
    const ushort_t* __restrict__ hs, float* __restrict__ out)
{
    const int b0 = blockIdx.x * 2;
    const int tid = threadIdx.x;
    const int j = tid;

    __shared__ __align__(16) float W_lds[128 * 258];   // proj_W padded (stride 258 -> 2-way max)
    __shared__ __align__(16) float g_lds[2][512];
    __shared__ __align__(16) float h_lds[2][128];
    __shared__ __align__(16) float q_lds[2][256];
    __shared__ __align__(16) float sc_lds[2][256];
    __shared__ __align__(16) float part_lds[8][256];
    __shared__ __align__(16) float wsum_lds[2][256];
    __shared__ __align__(16) float ctx_lds[2][128];
    __shared__ __align__(16) float comb_lds[2][128];

    for (int i = tid; i < 128 * 256; i += 512) {
        int uu = i >> 8, dd = i & 255;
        W_lds[uu * 258 + dd] = proj_W[i];
    }
    float4 w4[32];
    #pragma unroll
    for (int kc = 0; kc < 32; ++kc) {
        w4[kc].x = WhhT_d[(kc * 4 + 0) * 512 + j];
        w4[kc].y = WhhT_d[(kc * 4 + 1) * 512 + j];
        w4[kc].z = WhhT_d[(kc * 4 + 2) * 512 + j];
        w4[kc].w = WhhT_d[(kc * 4 + 3) * 512 + j];
    }
    const int rr1 = tid >> 7, u1 = tid & 127;   // valid when tid < 256
    float c = 0.f;
    if (tid < 256) {
        int b = b0 + rr1;
        c = cfin[b * 128 + u1] + cfin[65536 + b * 128 + u1];
        h_lds[rr1][u1] = hfin[b * 128 + u1] + hfin[65536 + b * 128 + u1];
    }
    __syncthreads();

    for (int t = 0; t < T_; ++t) {
        // ---- LSTM cell ----
        int tok0 = (t == 0) ? 0 : target[(b0 + 0) * T_ + t - 1];
        int tok1 = (t == 0) ? 0 : target[(b0 + 1) * T_ + t - 1];
        float a0 = xt_d[tok0 * 512 + j];
        float a1 = xt_d[tok1 * 512 + j];
        #pragma unroll
        for (int kc = 0; kc < 32; ++kc) {
            const float4 w = w4[kc];
            const float4 h0 = *reinterpret_cast<const float4*>(&h_lds[0][kc * 4]);
            const float4 h1 = *reinterpret_cast<const float4*>(&h_lds[1][kc * 4]);
            a0 = fmaf(h0.x, w.x, a0); a0 = fmaf(h0.y, w.y, a0); a0 = fmaf(h0.z, w.z, a0); a0 = fmaf(h0.w, w.w, a0);
            a1 = fmaf(h1.x, w.x, a1); a1 = fmaf(h1.y, w.y, a1); a1 = fmaf(h1.z, w.z, a1); a1 = fmaf(h1.w, w.w, a1);
        }
        g_lds[0][j] = a0; g_lds[1][j] = a1;
        __syncthreads();
        if (tid < 256) {
            float gi = g_lds[rr1][u1], gf = g_lds[rr1][u1 + 128];
            float gg = g_lds[rr1][u1 + 256], go = g_lds[rr1][u1 + 384];
            float ii = sigm(gi), ff = sigm(gf), g_ = tanh_(gg), oo = sigm(go);
            c = ff * c + ii * g_;
            h_lds[rr1][u1] = oo * tanh_(c);
        }
        __syncthreads();
        // ---- q = proj_W^T h  (scores_s = e_s . q; proj_b drops out of softmax) ----
        {
            int r = tid >> 8, d = tid & 255;
            float acc = 0.f;
            #pragma unroll 4
            for (int uu = 0; uu < 128; ++uu)
                acc = fmaf(W_lds[uu * 258 + d], h_lds[r][uu], acc);
            q_lds[r][d] = acc;
        }
        __syncthreads();
        // ---- scores: 4-lane group per s, lanes split d in 4x64 ----
        {
            int wave = tid >> 6, lane = tid & 63;
            int r = wave >> 2, wq = wave & 3, g16 = lane >> 2, dq = lane & 3;
            const ushort_t* hb = hs + (size_t)(b0 + r) * S_ * 256;
            #pragma unroll
            for (int p = 0; p < 4; ++p) {
                int s = wq * 64 + p * 16 + g16;
                const ushort_t* row = hb + (size_t)s * 256 + dq * 64;
                float acc = 0.f;
                #pragma unroll
                for (int it = 0; it < 16; ++it) {
                    uint2 uu = *reinterpret_cast<const uint2*>(row + it * 4);
                    float4 qv = *reinterpret_cast<const float4*>(&q_lds[r][dq * 64 + it * 4]);
                    acc = fmaf(bflo(uu.x), qv.x, acc);
                    acc = fmaf(bfhi(uu.x), qv.y, acc);
                    acc = fmaf(bflo(uu.y), qv.z, acc);
                    acc = fmaf(bfhi(uu.y), qv.w, acc);
                }
                acc += __shfl_xor(acc, 1);
                acc += __shfl_xor(acc, 2);
                if (dq == 0) sc_lds[r][s] = acc;
            }
        }
        __syncthreads();
        // ---- softmax over s (one wave per row) ----
        if (tid < 128) {
            int r = tid >> 6, lane = tid & 63;
            float4 sv = *reinterpret_cast<const float4*>(&sc_lds[r][lane * 4]);
            float m = fmaxf(fmaxf(sv.x, sv.y), fmaxf(sv.z, sv.w));
            #pragma unroll
            for (int o = 1; o < 64; o <<= 1) m = fmaxf(m, __shfl_xor(m, o));
            float e0 = fast_exp2((sv.x - m) * 1.4426950408889634f);
            float e1 = fast_exp2((sv.y - m) * 1.4426950408889634f);
            float e2 = fast_exp2((sv.z - m) * 1.4426950408889634f);
            float e3 = fast_exp2((sv.w - m) * 1.4426950408889634f);
            float ssum = e0 + e1 + e2 + e3;
            #pragma unroll
            for (int o = 1; o < 64; o <<= 1) ssum += __shfl_xor(ssum, o);
            float inv = fast_rcp(ssum);
            float4 r4 = make_float4(e0 * inv, e1 * inv, e2 * inv, e3 * inv);
            *reinterpret_cast<float4*>(&sc_lds[r][lane * 4]) = r4;
        }
        __syncthreads();
        // ---- weighted sum over s (lanes cover all 256 d, coalesced) ----
        {
            int wave = tid >> 6, lane = tid & 63;
            int r = wave >> 2, wq = wave & 3;
            const ushort_t* hb = hs + (size_t)(b0 + r) * S_ * 256 + lane * 4;
            float ax = 0.f, ay = 0.f, az = 0.f, aw_ = 0.f;
            #pragma unroll 4
            for (int s = wq * 64; s < wq * 64 + 64; ++s) {
                float awv = sc_lds[r][s];
                uint2 uu = *reinterpret_cast<const uint2*>(hb + (size_t)s * 256);
                ax = fmaf(bflo(uu.x), awv, ax);
                ay = fmaf(bfhi(uu.x), awv, ay);
                az = fmaf(bflo(uu.y), awv, az);
                aw_ = fmaf(bfhi(uu.y), awv, aw_);
            }
            *reinterpret_cast<float4*>(&part_lds[wave][lane * 4]) = make_float4(ax, ay, az, aw_);
        }
        __syncthreads();
        {
            int r = tid >> 8, d = tid & 255;
            wsum_lds[r][d] = part_lds[r * 4 + 0][d] + part_lds[r * 4 + 1][d] +
                             part_lds[r * 4 + 2][d] + part_lds[r * 4 + 3][d];
        }
        __syncthreads();
        // ---- ctx = proj_W * wsum + proj_b ----
        if (tid < 256) {
            float acc = proj_b[u1];
            #pragma unroll 4
            for (int k2 = 0; k2 < 128; ++k2) {
                float2 wv = *reinterpret_cast<const float2*>(&W_lds[u1 * 258 + k2 * 2]);
                float2 sv = *reinterpret_cast<const float2*>(&wsum_lds[rr1][k2 * 2]);
                acc = fmaf(wv.x, sv.x, acc);
                acc = fmaf(wv.y, sv.y, acc);
            }
            ctx_lds[rr1][u1] = acc;
        }
        __syncthreads();
        // ---- comb = tanh(attn_W [h;ctx] + attn_b) ----
        if (tid < 256) {
            float acc = attn_b[u1];
            #pragma unroll 4
            for (int k = 0; k < 128; ++k)
                acc = fmaf(attn_WT[k * 128 + u1], h_lds[rr1][k], acc);
            #pragma unroll 4
            for (int k = 0; k < 128; ++k)
                acc = fmaf(attn_WT[(128 + k) * 128 + u1], ctx_lds[rr1][k], acc);
            comb_lds[rr1][u1] = tanh_(acc);
        }
        __syncthreads();
        // ---- logits = out_W comb + out_b  (4 lanes per (r,v), k split) ----
        if (tid < 224) {
            int r = tid / 112, rem = tid % 112, v = rem >> 2, kq = rem & 3;
            float acc = 0.f;
            #pragma unroll 4
            for (int kk = 0; kk < 32; ++kk) {
                int k = kq * 32 + kk;
                acc = fmaf(out_WT[k * 28 + v], comb_lds[r][k], acc);
            }
            acc += __shfl_xor(acc, 1);
            acc += __shfl_xor(acc, 2);
            if (kq == 0)
                out[(size_t)(b0 + r) * (T_ * V_) + t * V_ + v] = acc + out_b[v];
        }
        __syncthreads();
    }
}

extern "C" void kernel_launch(void* const* d_in, const int* in_sizes, int n_in,
                              void* d_out, int out_size, void* d_ws, size_t ws_size,
                              hipStream_t stream) {
    const int* src      = (const int*)d_in[0];
    const int* target   = (const int*)d_in[1];
    const float* embed  = (const float*)d_in[2];
    const float* Wih_f  = (const float*)d_in[3];
    const float* Whh_f  = (const float*)d_in[4];
    const float* b_f    = (const float*)d_in[5];
    const float* Wih_b  = (const float*)d_in[6];
    const float* Whh_b  = (const float*)d_in[7];
    const float* b_b    = (const float*)d_in[8];
    const float* Wih_d  = (const float*)d_in[9];
    const float* Whh_d  = (const float*)d_in[10];
    const float* b_d    = (const float*)d_in[11];
    const float* proj_W = (const float*)d_in[12];
    const float* proj_b = (const float*)d_in[13];
    const float* attn_W = (const float*)d_in[14];
    const float* attn_b = (const float*)d_in[15];
    const float* out_W  = (const float*)d_in[16];
    const float* out_b  = (const float*)d_in[17];

    float* ws = (float*)d_ws;
    ushort_t* hs = (ushort_t*)((char*)d_ws + HS_BYTE_OFF);
    float* out = (float*)d_out;

    prep_kernel<<<(PREP_N + 255) / 256, 256, 0, stream>>>(
        embed, Wih_f, b_f, Wih_b, b_b, Wih_d, b_d,
        Whh_f, Whh_b, Whh_d, attn_W, out_W, ws);

    enc_kernel<<<dim3(128, 2), 512, 0, stream>>>(
        src, ws + XT_F, ws + WT_F, ws + HFIN, ws + CFIN, hs);

    dec_kernel<<<256, 512, 0, stream>>>(
        target, ws + XT_D, ws + WT_D, ws + HFIN, ws + CFIN,
        proj_W, proj_b, ws + AWT, attn_b, ws + OWT, out_b, hs, out);
}

// Round 2
// 814.536 us; speedup vs baseline: 3.4981x; 3.4981x over previous
//
#include <hip/hip_runtime.h>
#include <hip/hip_bf16.h>
#include <stdint.h>

typedef unsigned short ushort_t;
typedef unsigned int uint_t;

#define B_ 512
#define S_ 256
#define T_ 10
#define V_ 28
#define H_ 128

// ---- workspace layout (float element offsets) ----
#define XT_F   0
#define XT_B   14336
#define XT_D   28672
#define WT_F   43008
#define WT_B   108544
#define WT_D   174080
#define AWT    239616
#define OWT    272384
#define PWT    275968
#define HFIN   308736
#define CFIN   439808
#define HDEC   570880
#define FLOATS_END 1226240
#define HS_BYTE_OFF (1226240ull * 4ull)
#define PREP_N 308736

__device__ __forceinline__ float fast_exp2(float x) { return __builtin_amdgcn_exp2f(x); }
__device__ __forceinline__ float fast_rcp(float x)  { return __builtin_amdgcn_rcpf(x); }
__device__ __forceinline__ float sigm(float x) {
    return fast_rcp(1.f + fast_exp2(-1.4426950408889634f * x));
}
__device__ __forceinline__ float tanh_(float x) {
    return 1.f - 2.f * fast_rcp(1.f + fast_exp2(2.8853900817779268f * x));
}
__device__ __forceinline__ ushort_t f2bf(float x) {
    uint_t u = __float_as_uint(x);
    return (ushort_t)((u + 0x7FFFu + ((u >> 16) & 1u)) >> 16);  // RNE
}
__device__ __forceinline__ float bflo(uint_t u) { return __uint_as_float(u << 16); }
__device__ __forceinline__ float bfhi(uint_t u) { return __uint_as_float(u & 0xFFFF0000u); }

// ---------------- prep: xg tables + weight transposes ----------------
__global__ __launch_bounds__(256) void prep_kernel(
    const float* __restrict__ embed,
    const float* __restrict__ Wih_f, const float* __restrict__ b_f,
    const float* __restrict__ Wih_b, const float* __restrict__ b_b,
    const float* __restrict__ Wih_d, const float* __restrict__ b_d,
    const float* __restrict__ Whh_f, const float* __restrict__ Whh_b,
    const float* __restrict__ Whh_d,
    const float* __restrict__ attn_W, const float* __restrict__ out_W,
    const float* __restrict__ proj_W,
    float* __restrict__ ws)
{
    int i = blockIdx.x * 256 + threadIdx.x;
    if (i < 43008) {                       // xg tables: table[v][j] = b[j] + sum_e embed[v,e]*Wih[j,e]
        int tbl = i / 14336, rem = i % 14336;
        int v = rem >> 9, jj = rem & 511;
        const float* Wih = (tbl == 0) ? Wih_f : (tbl == 1) ? Wih_b : Wih_d;
        const float* bb  = (tbl == 0) ? b_f   : (tbl == 1) ? b_b   : b_d;
        float acc = bb[jj];
        #pragma unroll
        for (int e = 0; e < 32; ++e) acc = fmaf(embed[v * 32 + e], Wih[jj * 32 + e], acc);
        ws[tbl * 14336 + rem] = acc;
    } else if (i < 43008 + 196608) {       // WhhT[k][j] = Whh[j][k]
        int r = i - 43008; int tbl = r / 65536; int rem = r % 65536;
        int k = rem >> 9, jj = rem & 511;
        const float* Whh = (tbl == 0) ? Whh_f : (tbl == 1) ? Whh_b : Whh_d;
        ws[WT_F + tbl * 65536 + k * 512 + jj] = Whh[jj * 128 + k];
    } else if (i < OWT) {                  // attn_WT[k][u] = attn_W[u][k]
        int r = i - AWT; int k = r >> 7, uu = r & 127;
        ws[AWT + k * 128 + uu] = attn_W[uu * 256 + k];
    } else if (i < PWT) {                  // out_WT[k][v] = out_W[v][k]
        int r = i - OWT; int k = r / 28, v = r % 28;
        ws[OWT + k * 28 + v] = out_W[v * 128 + k];
    } else if (i < HFIN) {                 // projWT[k][u] = proj_W[u][k]
        int r = i - PWT; int k = r >> 7, uu = r & 127;
        ws[PWT + k * 128 + uu] = proj_W[uu * 256 + k];
    }
}

// ---------------- encoder: 1024 thr = (512 gates) x (2 k-halves), 4 rows/block ----------------
// w4[16] (64 VGPR) keeps total <=128 VGPR -> 16 waves/CU.
__global__ __launch_bounds__(1024, 4) void enc_kernel(
    const int* __restrict__ src,
    const float* __restrict__ xt_base,
    const float* __restrict__ wt_base,
    float* __restrict__ hfin_base,
    float* __restrict__ cfin_base,
    ushort_t* __restrict__ hs)
{
    const int dir = blockIdx.y;
    const int b0 = blockIdx.x * 4;
    const int tid = threadIdx.x;
    const int j = tid & 511, kh = tid >> 9;

    const float* xt   = xt_base + dir * 14336;
    const float* WhhT = wt_base + dir * 65536 + kh * 32768;

    __shared__ __align__(16) float parts[2][4][512];
    __shared__ __align__(16) float h_lds[4][128];
    __shared__ int tok_lds[4][256];

    for (int i = tid; i < 4 * 256; i += 1024)
        tok_lds[i >> 8][i & 255] = src[(b0 + (i >> 8)) * S_ + (i & 255)];
    if (tid < 512) h_lds[tid >> 7][tid & 127] = 0.f;

    float4 w4[16];
    #pragma unroll
    for (int kc = 0; kc < 16; ++kc) {
        w4[kc].x = WhhT[(kc * 4 + 0) * 512 + j];
        w4[kc].y = WhhT[(kc * 4 + 1) * 512 + j];
        w4[kc].z = WhhT[(kc * 4 + 2) * 512 + j];
        w4[kc].w = WhhT[(kc * 4 + 3) * 512 + j];
    }
    __syncthreads();

    float xa0 = 0.f, xa1 = 0.f, xa2 = 0.f, xa3 = 0.f;
    {
        int p0 = dir ? (S_ - 1) : 0;
        if (kh == 0) {
            xa0 = xt[tok_lds[0][p0] * 512 + j];
            xa1 = xt[tok_lds[1][p0] * 512 + j];
            xa2 = xt[tok_lds[2][p0] * 512 + j];
            xa3 = xt[tok_lds[3][p0] * 512 + j];
        }
    }
    float c = 0.f, hlast = 0.f;

    for (int t = 0; t < S_; ++t) {
        float a0 = xa0, a1 = xa1, a2 = xa2, a3 = xa3;
        if (t + 1 < S_ && kh == 0) {           // prefetch next step's xg
            int pn = dir ? (S_ - 2 - t) : (t + 1);
            xa0 = xt[tok_lds[0][pn] * 512 + j];
            xa1 = xt[tok_lds[1][pn] * 512 + j];
            xa2 = xt[tok_lds[2][pn] * 512 + j];
            xa3 = xt[tok_lds[3][pn] * 512 + j];
        }
        #pragma unroll
        for (int kc = 0; kc < 16; ++kc) {
            const float4 w = w4[kc];
            const float4 h0 = *reinterpret_cast<const float4*>(&h_lds[0][kh * 64 + kc * 4]);
            const float4 h1 = *reinterpret_cast<const float4*>(&h_lds[1][kh * 64 + kc * 4]);
            const float4 h2 = *reinterpret_cast<const float4*>(&h_lds[2][kh * 64 + kc * 4]);
            const float4 h3 = *reinterpret_cast<const float4*>(&h_lds[3][kh * 64 + kc * 4]);
            a0 = fmaf(h0.x, w.x, a0); a0 = fmaf(h0.y, w.y, a0); a0 = fmaf(h0.z, w.z, a0); a0 = fmaf(h0.w, w.w, a0);
            a1 = fmaf(h1.x, w.x, a1); a1 = fmaf(h1.y, w.y, a1); a1 = fmaf(h1.z, w.z, a1); a1 = fmaf(h1.w, w.w, a1);
            a2 = fmaf(h2.x, w.x, a2); a2 = fmaf(h2.y, w.y, a2); a2 = fmaf(h2.z, w.z, a2); a2 = fmaf(h2.w, w.w, a2);
            a3 = fmaf(h3.x, w.x, a3); a3 = fmaf(h3.y, w.y, a3); a3 = fmaf(h3.z, w.z, a3); a3 = fmaf(h3.w, w.w, a3);
        }
        parts[kh][0][j] = a0; parts[kh][1][j] = a1;
        parts[kh][2][j] = a2; parts[kh][3][j] = a3;
        __syncthreads();
        if (tid < 512) {
            int r = tid >> 7, u = tid & 127;
            int pos = dir ? (S_ - 1 - t) : t;
            float gi = parts[0][r][u]       + parts[1][r][u];
            float gf = parts[0][r][u + 128] + parts[1][r][u + 128];
            float gg = parts[0][r][u + 256] + parts[1][r][u + 256];
            float go = parts[0][r][u + 384] + parts[1][r][u + 384];
            float ii = sigm(gi), ff = sigm(gf), g_ = tanh_(gg), oo = sigm(go);
            c = ff * c + ii * g_;
            float h = oo * tanh_(c);
            hlast = h;
            h_lds[r][u] = h;
            hs[((size_t)(b0 + r) * S_ + pos) * 256 + dir * 128 + u] = f2bf(h);
        }
        __syncthreads();
    }
    if (tid < 512) {
        int r = tid >> 7, u = tid & 127;
        hfin_base[dir * 65536 + (b0 + r) * 128 + u] = hlast;
        cfin_base[dir * 65536 + (b0 + r) * 128 + u] = c;
    }
}

// ---------------- decoder LSTM only: 10 steps, store hdec[b][t][128] ----------------
__global__ __launch_bounds__(512, 2) void dec_lstm_kernel(
    const int* __restrict__ target,
    const float* __restrict__ xt_d,
    const float* __restrict__ WhhT_d,
    const float* __restrict__ hfin, const float* __restrict__ cfin,
    float* __restrict__ hdec)
{
    const int b0 = blockIdx.x * 2;
    const int tid = threadIdx.x;
    const int j = tid;

    __shared__ __align__(16) float h_lds[2][128];
    __shared__ __align__(16) float g_lds[2][512];

    float4 w4[32];
    #pragma unroll
    for (int kc = 0; kc < 32; ++kc) {
        w4[kc].x = WhhT_d[(kc * 4 + 0) * 512 + j];
        w4[kc].y = WhhT_d[(kc * 4 + 1) * 512 + j];
        w4[kc].z = WhhT_d[(kc * 4 + 2) * 512 + j];
        w4[kc].w = WhhT_d[(kc * 4 + 3) * 512 + j];
    }
    const int r1 = tid >> 7, u1 = tid & 127;
    float c = 0.f;
    if (tid < 256) {
        int b = b0 + r1;
        c = cfin[b * 128 + u1] + cfin[65536 + b * 128 + u1];
        h_lds[r1][u1] = hfin[b * 128 + u1] + hfin[65536 + b * 128 + u1];
    }
    __syncthreads();

    for (int t = 0; t < T_; ++t) {
        int tok0 = (t == 0) ? 0 : target[(b0 + 0) * T_ + t - 1];
        int tok1 = (t == 0) ? 0 : target[(b0 + 1) * T_ + t - 1];
        float a0 = xt_d[tok0 * 512 + j];
        float a1 = xt_d[tok1 * 512 + j];
        #pragma unroll
        for (int kc = 0; kc < 32; ++kc) {
            const float4 w = w4[kc];
            const float4 h0 = *reinterpret_cast<const float4*>(&h_lds[0][kc * 4]);
            const float4 h1 = *reinterpret_cast<const float4*>(&h_lds[1][kc * 4]);
            a0 = fmaf(h0.x, w.x, a0); a0 = fmaf(h0.y, w.y, a0); a0 = fmaf(h0.z, w.z, a0); a0 = fmaf(h0.w, w.w, a0);
            a1 = fmaf(h1.x, w.x, a1); a1 = fmaf(h1.y, w.y, a1); a1 = fmaf(h1.z, w.z, a1); a1 = fmaf(h1.w, w.w, a1);
        }
        g_lds[0][j] = a0; g_lds[1][j] = a1;
        __syncthreads();
        if (tid < 256) {
            float gi = g_lds[r1][u1], gf = g_lds[r1][u1 + 128];
            float gg = g_lds[r1][u1 + 256], go = g_lds[r1][u1 + 384];
            float ii = sigm(gi), ff = sigm(gf), g_ = tanh_(gg), oo = sigm(go);
            c = ff * c + ii * g_;
            float h = oo * tanh_(c);
            h_lds[r1][u1] = h;
            hdec[((size_t)(b0 + r1) * T_ + t) * 128 + u1] = h;
        }
        __syncthreads();
    }
}

// ---------------- attention + output, batched over all 10 t ----------------
__global__ __launch_bounds__(256, 2) void attn_kernel(
    const float* __restrict__ hdec,
    const float* __restrict__ projW, const float* __restrict__ proj_b,
    const float* __restrict__ projWT,
    const float* __restrict__ attn_WT, const float* __restrict__ attn_b,
    const float* __restrict__ out_WT, const float* __restrict__ out_b,
    const ushort_t* __restrict__ hs, float* __restrict__ out)
{
    const int b = blockIdx.x;
    const int tid = threadIdx.x;

    __shared__ __align__(16) float hd[1280];       // hdec[10][128]
    __shared__ __align__(16) float reg1[2560];     // q[10][256] -> ctx[10][128]+comb[10][128]
    __shared__ __align__(16) float sc[2560];       // scores -> aw [10][256]
    __shared__ __align__(16) float part[10240];    // wsum partials [4][10][256]
    __shared__ __align__(16) float wsum[2560];     // [10][256]

    const ushort_t* e = hs + (size_t)b * 65536;

    for (int i = tid; i < 1280; i += 256) hd[i] = hdec[(size_t)b * 1280 + i];
    __syncthreads();

    // phase 0: q[t][d] = sum_k hd[t][k] * projW[k][d]  (swizzle-stored)
    {
        float acc[10];
        #pragma unroll
        for (int t = 0; t < 10; ++t) acc[t] = 0.f;
        for (int k = 0; k < 128; ++k) {
            float pw = projW[k * 256 + tid];
            #pragma unroll
            for (int t = 0; t < 10; ++t) acc[t] = fmaf(hd[t * 128 + k], pw, acc[t]);
        }
        int swd = tid ^ ((((uint_t)tid >> 5) & 7) << 2);
        #pragma unroll
        for (int t = 0; t < 10; ++t) reg1[t * 256 + swd] = acc[t];
    }
    __syncthreads();

    // phase 1: scores[t][s] = e[s][:] . q[t][:]  (8 lanes per s, k8 owns 32 d)
    {
        const int w = tid >> 6, l = tid & 63;
        const int s3 = l >> 3, k8 = l & 7;
        for (int pass = 0; pass < 8; ++pass) {
            int s = w * 64 + pass * 8 + s3;
            const ushort_t* row = e + s * 256 + k8 * 32;
            uint4 e0 = *reinterpret_cast<const uint4*>(row);
            uint4 e1 = *reinterpret_cast<const uint4*>(row + 8);
            uint4 e2 = *reinterpret_cast<const uint4*>(row + 16);
            uint4 e3 = *reinterpret_cast<const uint4*>(row + 24);
            float acc[10];
            #pragma unroll
            for (int t = 0; t < 10; ++t) {
                const float* qb = &reg1[t * 256];
                float a = 0.f;
                #define QCH(i) (*reinterpret_cast<const float4*>(&qb[(k8 * 32 + (i) * 4) ^ (k8 << 2)]))
                #define DOT4(pa, pb, qv) { float4 q_ = (qv); \
                    a = fmaf(bflo(pa), q_.x, a); a = fmaf(bfhi(pa), q_.y, a); \
                    a = fmaf(bflo(pb), q_.z, a); a = fmaf(bfhi(pb), q_.w, a); }
                DOT4(e0.x, e0.y, QCH(0)); DOT4(e0.z, e0.w, QCH(1));
                DOT4(e1.x, e1.y, QCH(2)); DOT4(e1.z, e1.w, QCH(3));
                DOT4(e2.x, e2.y, QCH(4)); DOT4(e2.z, e2.w, QCH(5));
                DOT4(e3.x, e3.y, QCH(6)); DOT4(e3.z, e3.w, QCH(7));
                #undef QCH
                #undef DOT4
                acc[t] = a;
            }
            #pragma unroll
            for (int t = 0; t < 10; ++t) {
                acc[t] += __shfl_xor(acc[t], 1);
                acc[t] += __shfl_xor(acc[t], 2);
                acc[t] += __shfl_xor(acc[t], 4);
            }
            if (k8 == 0) {
                #pragma unroll
                for (int t = 0; t < 10; ++t) sc[t * 256 + s] = acc[t];
            }
        }
    }
    __syncthreads();

    // phase 2: softmax per (t) row over 256 s
    {
        const int w = tid >> 6, l = tid & 63;
        for (int t = w; t < 10; t += 4) {
            float4 sv = *reinterpret_cast<const float4*>(&sc[t * 256 + l * 4]);
            float m = fmaxf(fmaxf(sv.x, sv.y), fmaxf(sv.z, sv.w));
            #pragma unroll
            for (int o = 1; o < 64; o <<= 1) m = fmaxf(m, __shfl_xor(m, o));
            float e0 = fast_exp2((sv.x - m) * 1.4426950408889634f);
            float e1 = fast_exp2((sv.y - m) * 1.4426950408889634f);
            float e2 = fast_exp2((sv.z - m) * 1.4426950408889634f);
            float e3 = fast_exp2((sv.w - m) * 1.4426950408889634f);
            float ssum = e0 + e1 + e2 + e3;
            #pragma unroll
            for (int o = 1; o < 64; o <<= 1) ssum += __shfl_xor(ssum, o);
            float inv = fast_rcp(ssum);
            *reinterpret_cast<float4*>(&sc[t * 256 + l * 4]) =
                make_float4(e0 * inv, e1 * inv, e2 * inv, e3 * inv);
        }
    }
    __syncthreads();

    // phase 3: wsum partials: wave w covers s-quarter, lane owns 4 d, all 10 t
    {
        const int w = tid >> 6, l = tid & 63;
        float ax[10], ay[10], az[10], aw2[10];
        #pragma unroll
        for (int t = 0; t < 10; ++t) { ax[t] = 0.f; ay[t] = 0.f; az[t] = 0.f; aw2[t] = 0.f; }
        const ushort_t* col = e + l * 4;
        for (int s = w * 64; s < w * 64 + 64; ++s) {
            uint2 uu = *reinterpret_cast<const uint2*>(col + (size_t)s * 256);
            float v0 = bflo(uu.x), v1 = bfhi(uu.x), v2 = bflo(uu.y), v3 = bfhi(uu.y);
            #pragma unroll
            for (int t = 0; t < 10; ++t) {
                float awv = sc[t * 256 + s];
                ax[t] = fmaf(v0, awv, ax[t]); ay[t] = fmaf(v1, awv, ay[t]);
                az[t] = fmaf(v2, awv, az[t]); aw2[t] = fmaf(v3, awv, aw2[t]);
            }
        }
        #pragma unroll
        for (int t = 0; t < 10; ++t)
            *reinterpret_cast<float4*>(&part[(w * 10 + t) * 256 + l * 4]) =
                make_float4(ax[t], ay[t], az[t], aw2[t]);
    }
    __syncthreads();

    // phase 4: reduce partials
    for (int i = tid; i < 2560; i += 256)
        wsum[i] = part[i] + part[2560 + i] + part[5120 + i] + part[7680 + i];
    __syncthreads();

    // phase 5: ctx[t][u] = proj_b[u] + sum_k projW[u][k] wsum[t][k]   -> reg1[0..1280)
    {
        const int u = tid & 127, th = tid >> 7;
        float acc[5];
        #pragma unroll
        for (int i = 0; i < 5; ++i) acc[i] = proj_b[u];
        for (int k = 0; k < 256; ++k) {
            float pw = projWT[k * 128 + u];
            #pragma unroll
            for (int i = 0; i < 5; ++i) acc[i] = fmaf(pw, wsum[(th * 5 + i) * 256 + k], acc[i]);
        }
        #pragma unroll
        for (int i = 0; i < 5; ++i) reg1[(th * 5 + i) * 128 + u] = acc[i];
    }
    __syncthreads();

    // phase 6: comb[t][u] = tanh(attn_b[u] + attnW[u][:128].h[t] + attnW[u][128:].ctx[t]) -> reg1[1280..)
    {
        const int u = tid & 127, th = tid >> 7;
        float acc[5];
        #pragma unroll
        for (int i = 0; i < 5; ++i) acc[i] = attn_b[u];
        for (int k = 0; k < 128; ++k) {
            float a1 = attn_WT[k * 128 + u];
            #pragma unroll
            for (int i = 0; i < 5; ++i) acc[i] = fmaf(a1, hd[(th * 5 + i) * 128 + k], acc[i]);
        }
        for (int k = 0; k < 128; ++k) {
            float a2 = attn_WT[(128 + k) * 128 + u];
            #pragma unroll
            for (int i = 0; i < 5; ++i) acc[i] = fmaf(a2, reg1[(th * 5 + i) * 128 + k], acc[i]);
        }
        #pragma unroll
        for (int i = 0; i < 5; ++i) reg1[1280 + (th * 5 + i) * 128 + u] = tanh_(acc[i]);
    }
    __syncthreads();

    // phase 7: logits
    for (int o = tid; o < 280; o += 256) {
        int t = o / 28, v = o - t * 28;
        float acc = out_b[v];
        #pragma unroll 4
        for (int k = 0; k < 128; ++k)
            acc = fmaf(out_WT[k * 28 + v], reg1[1280 + t * 128 + k], acc);
        out[(size_t)b * 280 + o] = acc;
    }
}

extern "C" void kernel_launch(void* const* d_in, const int* in_sizes, int n_in,
                              void* d_out, int out_size, void* d_ws, size_t ws_size,
                              hipStream_t stream) {
    const int* src      = (const int*)d_in[0];
    const int* target   = (const int*)d_in[1];
    const float* embed  = (const float*)d_in[2];
    const float* Wih_f  = (const float*)d_in[3];
    const float* Whh_f  = (const float*)d_in[4];
    const float* b_f    = (const float*)d_in[5];
    const float* Wih_b  = (const float*)d_in[6];
    const float* Whh_b  = (const float*)d_in[7];
    const float* b_b    = (const float*)d_in[8];
    const float* Wih_d  = (const float*)d_in[9];
    const float* Whh_d  = (const float*)d_in[10];
    const float* b_d    = (const float*)d_in[11];
    const float* proj_W = (const float*)d_in[12];
    const float* proj_b = (const float*)d_in[13];
    const float* attn_W = (const float*)d_in[14];
    const float* attn_b = (const float*)d_in[15];
    const float* out_W  = (const float*)d_in[16];
    const float* out_b  = (const float*)d_in[17];

    float* ws = (float*)d_ws;
    ushort_t* hs = (ushort_t*)((char*)d_ws + HS_BYTE_OFF);
    float* out = (float*)d_out;

    prep_kernel<<<PREP_N / 256, 256, 0, stream>>>(
        embed, Wih_f, b_f, Wih_b, b_b, Wih_d, b_d,
        Whh_f, Whh_b, Whh_d, attn_W, out_W, proj_W, ws);

    enc_kernel<<<dim3(128, 2), 1024, 0, stream>>>(
        src, ws + XT_F, ws + WT_F, ws + HFIN, ws + CFIN, hs);

    dec_lstm_kernel<<<256, 512, 0, stream>>>(
        target, ws + XT_D, ws + WT_D, ws + HFIN, ws + CFIN, ws + HDEC);

    attn_kernel<<<512, 256, 0, stream>>>(
        ws + HDEC, proj_W, proj_b, ws + PWT, ws + AWT, attn_b,
        ws + OWT, out_b, hs, out);
}